// Round 15
// baseline (5289.761 us; speedup 1.0000x reference)
//
#include <hip/hip_runtime.h>
#include <hip/hip_bf16.h>
#include <stdint.h>

// GRU-D encoder, MI355X, round 15: ONE cross-WG hop per step.
// B=256, S=200, D=64, H=512, TD=8.
// Each of the 4 gate WGs per rb computes the FULL 512-wide r redundantly
// (Ur streamed from L2 as pre-packed bf16 panel frags), keeps rh intra-WG
// in LDS, then computes its own 128 output cols of Uh/z/gamma (resident
// weights), blends, and publishes h_dec(t+1) (parity double-buffered).
// Only flag: FH[16] per rb. 2 barriers/step. Fuel-bounded polls.

typedef unsigned short u16;
typedef unsigned int   u32;
typedef unsigned long long u64;
typedef short bfrag  __attribute__((ext_vector_type(8)));
typedef u16   u16x8  __attribute__((ext_vector_type(8)));
typedef float f32x4  __attribute__((ext_vector_type(4)));

#define NB 256
#define NS 200
#define ND 64
#define NH 512

#define MFMA(a,b,c) __builtin_amdgcn_mfma_f32_16x16x32_bf16((a),(b),(c),0,0,0)

union UQ { u16x8 h; bfrag s; u64 u[2]; uint4 q; };

__device__ __forceinline__ float b2f(u16 v){ union { float f; u32 u; } c; c.u = ((u32)v) << 16; return c.f; }
__device__ __forceinline__ u16 f2b(float f){ union { float f; u32 u; } c; c.f = f; u32 r = c.u + 0x7FFFu + ((c.u >> 16) & 1u); return (u16)(r >> 16); }
__device__ __forceinline__ float sigm(float x){ return 1.f / (1.f + __expf(-x)); }
__device__ __forceinline__ float tanh_f(float x){ return 1.f - 2.f / (1.f + __expf(2.f * x)); }

// agent-scope (coherence-point) ops for intra-kernel cross-WG data
__device__ __forceinline__ u64 cload64(const void* p){
  return __hip_atomic_load((const u64*)p, __ATOMIC_RELAXED, __HIP_MEMORY_SCOPE_AGENT);
}
__device__ __forceinline__ void cstore64(void* p, u64 v){
  __hip_atomic_store((u64*)p, v, __ATOMIC_RELAXED, __HIP_MEMORY_SCOPE_AGENT);
}
__device__ __forceinline__ u32 cload32(const u32* p){
  return __hip_atomic_load(p, __ATOMIC_RELAXED, __HIP_MEMORY_SCOPE_AGENT);
}
__device__ __forceinline__ void cstore32(u32* p, u32 v){
  __hip_atomic_store(p, v, __ATOMIC_RELAXED, __HIP_MEMORY_SCOPE_AGENT);
}
// lane-parallel poll with backoff, fuel-bounded (fail fast, no GPU hang)
__device__ __forceinline__ bool poll_ge(const u32* wp, u32 tgt){
  int fuel = 1 << 19;
  while (true) {
    u32 v = cload32(wp);
    if (__all(v >= tgt)) return true;
    __builtin_amdgcn_s_sleep(1);
    if (--fuel == 0) return false;
  }
}
__device__ __forceinline__ bfrag ldfrag(const float* src){
  f32x4 lo = *(const f32x4*)src;
  f32x4 hi = *(const f32x4*)(src + 4);
  UQ z;
  z.h[0]=f2b(lo[0]); z.h[1]=f2b(lo[1]); z.h[2]=f2b(lo[2]); z.h[3]=f2b(lo[3]);
  z.h[4]=f2b(hi[0]); z.h[5]=f2b(hi[1]); z.h[6]=f2b(hi[2]); z.h[7]=f2b(hi[3]);
  return z.s;
}
// cooperative staging of a [16][512] bf16 block into an A-panel (R13 proven)
__device__ __forceinline__ void stage_bf16(u16* dst, const u16* src, int tid, bool zero){
  const int row = tid >> 4, sc = (tid & 15) * 32;
  u16* dp = &dst[((sc >> 3) * 16 + row) * 8];
  if (!zero) {
    const u16* hs = src + (size_t)row * 512 + sc;
    u64 a0 = cload64(hs),      a1 = cload64(hs + 4),  a2 = cload64(hs + 8),  a3 = cload64(hs + 12);
    u64 a4 = cload64(hs + 16), a5 = cload64(hs + 20), a6 = cload64(hs + 24), a7 = cload64(hs + 28);
    *(u64*)(dp)       = a0; *(u64*)(dp + 4)   = a1;
    *(u64*)(dp + 128) = a2; *(u64*)(dp + 132) = a3;
    *(u64*)(dp + 256) = a4; *(u64*)(dp + 260) = a5;
    *(u64*)(dp + 384) = a6; *(u64*)(dp + 388) = a7;
  } else {
    *(u64*)(dp)       = 0; *(u64*)(dp + 4)   = 0;
    *(u64*)(dp + 128) = 0; *(u64*)(dp + 132) = 0;
    *(u64*)(dp + 256) = 0; *(u64*)(dp + 260) = 0;
    *(u64*)(dp + 384) = 0; *(u64*)(dp + 388) = 0;
  }
}

// ---------------- setup kernels ----------------

__global__ void transpose_k(const float* __restrict__ Wout, float* __restrict__ WT){
  int i = blockIdx.x * 256 + threadIdx.x;
  if (i < 520 * 512) { int k = i >> 9, ho = i & 511; WT[i] = Wout[ho * 520 + k]; }
}

// pre-pack Ur (rows 512..1024 of U) into bf16 MFMA B-frag panel layout:
// UrP[((cf*16+kk)*64 + l)*8 + j] = bf16(U[512 + cf*16 + (l&15)][kk*32 + (l>>4)*8 + j])
__global__ void wconv_k(const float* __restrict__ Um, u16* __restrict__ UrP){
  int idx = blockIdx.x * 256 + threadIdx.x;   // over 512 frags x 64 lanes
  if (idx < 512 * 64) {
    const int l = idx & 63, fk = idx >> 6;
    const int cf = fk >> 4, kk = fk & 15;
    const float* src = Um + (size_t)(512 + cf * 16 + (l & 15)) * 512 + kk * 32 + (l >> 4) * 8;
    u16* dst = UrP + (size_t)idx * 8;
    #pragma unroll
    for (int j = 0; j < 8; ++j) dst[j] = f2b(src[j]);
  }
}

__global__ void mean1_k(const float* __restrict__ x, const float* __restrict__ mask,
                        float* __restrict__ PX, float* __restrict__ PM){
  int s = blockIdx.x, tid = threadIdx.x;
  __shared__ float lx[256], lm[256];
  float xa = 0.f, ma = 0.f;
  for (int i = tid; i < NB * ND; i += 256) {
    int b = i >> 6, d = i & 63;
    size_t ix = ((size_t)b * NS + s) * 64 + d;
    float m = mask[ix];
    xa += m * x[ix]; ma += m;
  }
  lx[tid] = xa; lm[tid] = ma;
  __syncthreads();
  if (tid < 64) {
    PX[(size_t)s * 64 + tid] = lx[tid] + lx[tid + 64] + lx[tid + 128] + lx[tid + 192];
    PM[(size_t)s * 64 + tid] = lm[tid] + lm[tid + 64] + lm[tid + 128] + lm[tid + 192];
  }
}

__global__ void mean2_k(const float* __restrict__ PX, const float* __restrict__ PM,
                        float* __restrict__ XMEAN){
  int d = threadIdx.x;
  float sx = 0.f, sm = 0.f;
  for (int s = 0; s < NS; ++s){ sx += PX[s * 64 + d]; sm += PM[s * 64 + d]; }
  XMEAN[d] = sx / fmaxf(sm, 1.f);
}

__global__ void prep_k(const float* __restrict__ x, const float* __restrict__ mask,
                       const float* __restrict__ tc, const float* __restrict__ wdgx,
                       const float* __restrict__ bdgx, const float* __restrict__ XMEAN,
                       u16* __restrict__ XHAT, u16* __restrict__ MASKB, u16* __restrict__ DELTA){
  int g = blockIdx.x * 256 + threadIdx.x;
  int b = g >> 6, d = g & 63;
  float xmean = XMEAN[d], wx = wdgx[d], bx = bdgx[d];
  float xl = 0.f, del = 0.f, tprev = 0.f, mprev = 1.f;
  for (int s = 0; s < NS; ++s){
    float tv = tc[b * NS + s];
    float dtv = (s == 0) ? 0.f : (tv - tprev);
    tprev = tv;
    del = dtv + (1.f - mprev) * del;
    size_t ix = ((size_t)b * NS + s) * 64 + d;
    float m = mask[ix], xv = x[ix];
    float gx = __expf(-fmaxf(0.f, wx * del + bx));
    float xh = m * xv + (1.f - m) * (gx * xl + (1.f - gx) * xmean);
    size_t ox = ((size_t)s * NB + b) * 64 + d;
    XHAT[ox] = f2b(xh); MASKB[ox] = f2b(m); DELTA[ox] = f2b(del);
    xl = m * xv + (1.f - m) * xl;
    mprev = m;
  }
}

// ---------------- XP precompute ----------------
__global__ __launch_bounds__(256, 1) void xpart_k(
    const float* __restrict__ Wm, const float* __restrict__ Vm,
    const float* __restrict__ bv, const u16* __restrict__ XHAT,
    const u16* __restrict__ MASKB, u16* __restrict__ XP){
  const int tid = threadIdx.x, lane = tid & 63, wid = tid >> 6;
  const int l16 = lane & 15, krow = lane >> 4, r4 = lane >> 2, cb = (lane & 3) * 8;
  const int chunk = blockIdx.x >> 1, p = blockIdx.x & 1;
  const int R0 = chunk * 128;
  const int wbasel = wid * 192;
  const int wbaseg = p * 768 + wbasel;
  __shared__ u16 panel[16 * 16 * 8];
  __shared__ u16 outs[16][768];
  __shared__ float xb[4][16 * 33];
  float* xw = xb[wid];
  const f32x4 Z4 = {0.f, 0.f, 0.f, 0.f};

  bfrag BW[12][2], BV2[12][2];
  #pragma unroll
  for (int ct = 0; ct < 12; ++ct)
    #pragma unroll
    for (int kx = 0; kx < 2; ++kx) {
      BW[ct][kx]  = ldfrag(Wm + (size_t)(wbaseg + ct * 16 + l16) * 64 + kx * 32 + krow * 8);
      BV2[ct][kx] = ldfrag(Vm + (size_t)(wbaseg + ct * 16 + l16) * 64 + kx * 32 + krow * 8);
    }
  float bias6[6][8];
  #pragma unroll
  for (int grp = 0; grp < 6; ++grp)
    #pragma unroll
    for (int q = 0; q < 8; ++q) bias6[grp][q] = bv[wbaseg + grp * 32 + cb + q];

  for (int it = 0; it < 8; ++it) {
    const int R = R0 + it * 16;
    { const int kb = tid >> 4, row = tid & 15;
      const u16* sp = (kb < 8 ? XHAT : MASKB) + (size_t)(R + row) * 64 + (kb & 7) * 8;
      *(uint4*)&panel[(kb * 16 + row) * 8] = *(const uint4*)sp; }
    __syncthreads();
    #pragma unroll
    for (int grp = 0; grp < 6; ++grp) {
      f32x4 ac0 = Z4, ac1 = Z4;
      #pragma unroll
      for (int kx = 0; kx < 2; ++kx) {
        bfrag ax = *(const bfrag*)&panel[((kx * 4 + krow) * 16 + l16) * 8];
        ac0 = MFMA(ax, BW[grp*2][kx], ac0); ac1 = MFMA(ax, BW[grp*2+1][kx], ac1);
        bfrag am = *(const bfrag*)&panel[((8 + kx * 4 + krow) * 16 + l16) * 8];
        ac0 = MFMA(am, BV2[grp*2][kx], ac0); ac1 = MFMA(am, BV2[grp*2+1][kx], ac1);
      }
      #pragma unroll
      for (int j = 0; j < 4; ++j) { xw[(krow*4+j)*33 + l16] = ac0[j]; xw[(krow*4+j)*33 + 16 + l16] = ac1[j]; }
      UQ ov;
      #pragma unroll
      for (int q = 0; q < 8; ++q) ov.h[q] = f2b(xw[r4 * 33 + cb + q] + bias6[grp][q]);
      *(u64*)&outs[r4][wbasel + grp * 32 + cb] = ov.u[0];
      *(u64*)&outs[r4][wbasel + grp * 32 + cb + 4] = ov.u[1];
    }
    __syncthreads();
    for (int c = tid; c < 16 * 96; c += 256) {
      const int row = c / 96, ch = c % 96;
      *(uint4*)(XP + (size_t)(R + row) * 1536 + p * 768 + ch * 8) =
          *(const uint4*)&outs[row][ch * 8];
    }
    __syncthreads();
  }
}

// ---------------- persistent recurrent kernel (1 hop/step) ----------------
// grid = 64 WGs (16 rb x 4 gate WGs), 256 threads (4 waves).
// XCD map: lid = (bid&7)*8 + (bid>>3); rb = lid>>2; g = lid&3.
// Wave: full-width r cols [wid*128, +128) (Ur streamed from UrP);
//       own output cols cout = g*128 + wid*32 for z, h, gamma (resident).
// HDEC2: parity double-buffered [2][256][512] row-major.
// Flags per rb (stride 32): FH[16]. 2 barriers/step.
__global__ __launch_bounds__(256, 1) void grud_rnn(
    const float* __restrict__ Um, const u16* __restrict__ UrP,
    const float* __restrict__ Wdg, const float* __restrict__ bdg,
    const u16* __restrict__ XP, const u16* __restrict__ DELTA,
    u16* __restrict__ HDEC2, u16* __restrict__ HALL, u32* __restrict__ flags)
{
  const int tid = threadIdx.x, lane = tid & 63, wid = tid >> 6, bid = blockIdx.x;
  const int lid = (bid & 7) * 8 + (bid >> 3);
  const int rb = lid >> 2, g = lid & 3, m0 = rb * 16;
  const int l16 = lane & 15, krow = lane >> 4, r4 = lane >> 2, cb = (lane & 3) * 8;
  const int pw = g * 4 + wid;
  const int cout = g * 128 + wid * 32;   // own output cols (z, h, gamma)
  const int rcb = wid * 128;             // wave's r col window (full-width split)
  u32* FB = flags + rb * 32;

  __shared__ u16 hpan[64 * 16 * 8];      // h_dec(t) A-panel (16 KB)
  __shared__ u16 rpan[64 * 16 * 8];      // rh A-panel, intra-WG (16 KB)
  __shared__ u16 dpan[8 * 16 * 8];       // delta(t+1) A-panel (2 KB)
  __shared__ float xb[4][16 * 33];
  __shared__ int s_ab;
  float* xw = xb[wid];
  const f32x4 Z4 = {0.f, 0.f, 0.f, 0.f};
  if (tid == 0) s_ab = 0;
  __syncthreads();

  // resident weights: Uz/Uh for own 32 cols + Wdg (68 frags = 272 regs)
  bfrag BZ[16][2], BH[16][2], BG[2][2];
  #pragma unroll
  for (int kk = 0; kk < 16; ++kk) {
    const size_t ko = (size_t)(kk * 32 + krow * 8);
    #pragma unroll
    for (int t2 = 0; t2 < 2; ++t2) {
      BZ[kk][t2] = ldfrag(Um + (size_t)(       cout + t2 * 16 + l16) * 512 + ko);
      BH[kk][t2] = ldfrag(Um + (size_t)(1024 + cout + t2 * 16 + l16) * 512 + ko);
    }
  }
  #pragma unroll
  for (int kk = 0; kk < 2; ++kk)
    #pragma unroll
    for (int t2 = 0; t2 < 2; ++t2)
      BG[kk][t2] = ldfrag(Wdg + (size_t)(cout + t2 * 16 + l16) * 64 + kk * 32 + krow * 8);
  float gb8[8];
  #pragma unroll
  for (int q = 0; q < 8; ++q) gb8[q] = bdg[cout + cb + q];

  for (int t = 0; t < NS; ++t) {
    const int tn = (t + 1 < NS) ? t + 1 : NS - 1;
    // static per-t loads before the poll (plain cached)
    const u16* xp = XP + ((size_t)t * NB + m0 + r4) * 1536;
    u64 xz0 = *(const u64*)(xp + cout + cb),        xz1 = *(const u64*)(xp + cout + cb + 4);
    u64 xh0 = *(const u64*)(xp + 1024 + cout + cb), xh1 = *(const u64*)(xp + 1024 + cout + cb + 4);
    u64 xr0[4], xr1[4];
    #pragma unroll
    for (int cp = 0; cp < 4; ++cp) {
      xr0[cp] = *(const u64*)(xp + 512 + rcb + cp * 32 + cb);
      xr1[cp] = *(const u64*)(xp + 512 + rcb + cp * 32 + cb + 4);
    }
    // ---- THE hop: all-lane FH poll, then stage h_dec(t) ----
    if (t > 0) { if (!poll_ge(FB + (lane & 15), (u32)t)) s_ab = 1; }
    stage_bf16(hpan, HDEC2 + (size_t)(t & 1) * NB * 512 + (size_t)m0 * 512, tid, t == 0);
    if (tid < 128) {
      const int kb = tid >> 4, row = tid & 15;
      const u16* sp = DELTA + ((size_t)tn * NB + m0 + row) * 64 + kb * 8;
      *(uint4*)&dpan[(kb * 16 + row) * 8] = *(const uint4*)sp;
    }
    __syncthreads();                          // B1
    if (s_ab) break;
    // reads from hpan/dpan needed after B2 -> pull into registers now
    UQ hdo; hdo.h = *(const u16x8*)&hpan[(((cout + cb) >> 3) * 16 + r4) * 8];
    bfrag da0 = *(const bfrag*)&dpan[((krow) * 16 + l16) * 8];
    bfrag da1 = *(const bfrag*)&dpan[((4 + krow) * 16 + l16) * 8];
    // ---- full-width r GEMM (128 MFMA, Ur streamed from L2) ----
    f32x4 ra[8] = {Z4, Z4, Z4, Z4, Z4, Z4, Z4, Z4};
    #pragma unroll
    for (int kk = 0; kk < 16; ++kk) {
      bfrag a = *(const bfrag*)&hpan[((kk * 4 + krow) * 16 + l16) * 8];
      #pragma unroll
      for (int c = 0; c < 8; ++c) {
        bfrag b = *(const bfrag*)(UrP + ((size_t)((wid * 8 + c) * 16 + kk) * 64 + lane) * 8);
        ra[c] = MFMA(a, b, ra[c]);
      }
    }
    // ---- z GEMM (resident, own cols) ----
    f32x4 az0 = Z4, az1 = Z4;
    #pragma unroll
    for (int kk = 0; kk < 16; ++kk) {
      bfrag a = *(const bfrag*)&hpan[((kk * 4 + krow) * 16 + l16) * 8];
      az0 = MFMA(a, BZ[kk][0], az0); az1 = MFMA(a, BZ[kk][1], az1);
    }
    // ---- gamma GEMM (register frags) ----
    f32x4 g0 = Z4, g1 = Z4;
    g0 = MFMA(da0, BG[0][0], g0); g0 = MFMA(da1, BG[1][0], g0);
    g1 = MFMA(da0, BG[0][1], g1); g1 = MFMA(da1, BG[1][1], g1);
    // ---- rh epilogue: 4 windows of 32 cols -> rpan (intra-WG) ----
    #pragma unroll
    for (int cp = 0; cp < 4; ++cp) {
      #pragma unroll
      for (int j = 0; j < 4; ++j) {
        xw[(krow * 4 + j) * 33 + l16] = ra[2 * cp][j];
        xw[(krow * 4 + j) * 33 + 16 + l16] = ra[2 * cp + 1][j];
      }
      const int wc = rcb + cp * 32 + cb;
      UQ hdw; hdw.h = *(const u16x8*)&hpan[((wc >> 3) * 16 + r4) * 8];
      UQ xrw; xrw.u[0] = xr0[cp]; xrw.u[1] = xr1[cp];
      UQ rhv;
      #pragma unroll
      for (int q = 0; q < 8; ++q) {
        float rv = sigm(b2f(xrw.h[q]) + xw[r4 * 33 + cb + q]);
        rhv.h[q] = f2b(rv * b2f(hdw.h[q]));
      }
      *(u16x8*)&rpan[((wc >> 3) * 16 + r4) * 8] = rhv.h;
    }
    __syncthreads();                          // B2 (rpan complete)
    // ---- Uh GEMM (resident, own cols; A from rpan) ----
    f32x4 ah0 = Z4, ah1 = Z4;
    #pragma unroll
    for (int kk = 0; kk < 16; ++kk) {
      bfrag a = *(const bfrag*)&rpan[((kk * 4 + krow) * 16 + l16) * 8];
      ah0 = MFMA(a, BH[kk][0], ah0); ah1 = MFMA(a, BH[kk][1], ah1);
    }
    // ---- epilogue: hh, zf, gm transposes (wave-private xw, sequential) ----
    #pragma unroll
    for (int j = 0; j < 4; ++j) { xw[(krow*4+j)*33 + l16] = ah0[j]; xw[(krow*4+j)*33 + 16 + l16] = ah1[j]; }
    float hh[8];
    #pragma unroll
    for (int q = 0; q < 8; ++q) hh[q] = xw[r4 * 33 + cb + q];
    #pragma unroll
    for (int j = 0; j < 4; ++j) { xw[(krow*4+j)*33 + l16] = az0[j]; xw[(krow*4+j)*33 + 16 + l16] = az1[j]; }
    UQ xz_; xz_.u[0] = xz0; xz_.u[1] = xz1;
    float zf[8];
    #pragma unroll
    for (int q = 0; q < 8; ++q) zf[q] = sigm(b2f(xz_.h[q]) + xw[r4 * 33 + cb + q]);
    #pragma unroll
    for (int j = 0; j < 4; ++j) { xw[(krow*4+j)*33 + l16] = g0[j]; xw[(krow*4+j)*33 + 16 + l16] = g1[j]; }
    float gm8[8];
    #pragma unroll
    for (int q = 0; q < 8; ++q)
      gm8[q] = __expf(-fmaxf(0.f, xw[r4 * 33 + cb + q] + gb8[q]));
    // ---- blend + publish h_dec(t+1) ----
    UQ xh_; xh_.u[0] = xh0; xh_.u[1] = xh1;
    UQ hw_, hdn_;
    #pragma unroll
    for (int q = 0; q < 8; ++q) {
      float til = tanh_f(b2f(xh_.h[q]) + hh[q]);
      float hn = (1.f - zf[q]) * b2f(hdo.h[q]) + zf[q] * til;
      hw_.h[q] = f2b(hn);
      hdn_.h[q] = f2b(gm8[q] * hn);
    }
    if (t + 1 < NS) {
      u16* hdst = HDEC2 + (size_t)((t + 1) & 1) * NB * 512 + (size_t)(m0 + r4) * 512 + cout + cb;
      cstore64(hdst, hdn_.u[0]); cstore64(hdst + 4, hdn_.u[1]);
    }
    asm volatile("s_waitcnt vmcnt(0)" ::: "memory");
    if (lane == 0) cstore32(FB + pw, (u32)(t + 1));
    // HALL off critical path; [b][s][h] for coalesced attn reads
    u16* hp = HALL + ((size_t)(m0 + r4) * NS + t) * 512 + cout + cb;
    *(u64*)hp = hw_.u[0]; *(u64*)(hp + 4) = hw_.u[1];
    // no end barrier: hpan/dpan reads all in [B1,B2]; rpan written next
    // step only after next B1; overwrite of HDEC2 parity is lag-2-safe.
  }
}

// ---------------- post kernels ----------------

// HALL is [b][s][h]; all reads coalesced.
__global__ __launch_bounds__(256) void attn_k(const u16* __restrict__ HALL,
                                              const float* __restrict__ av,
                                              float* __restrict__ ATTN){
  const int b = blockIdx.x, tid = threadIdx.x, lane = tid & 63, wid = tid >> 6;
  __shared__ float avs[512], sc[256], wgt[256], red[8];
  for (int i = tid; i < 512; i += 256) avs[i] = av[i];
  __syncthreads();
  const u16* base = HALL + (size_t)b * NS * 512;
  for (int i = 0; i < 50; ++i) {
    const int s = wid * 50 + i;
    UQ w8; w8.q = *(const uint4*)(base + (size_t)s * 512 + lane * 8);
    float p = 0.f;
    #pragma unroll
    for (int j = 0; j < 8; ++j) p += b2f(w8.h[j]) * avs[lane * 8 + j];
    #pragma unroll
    for (int off = 32; off; off >>= 1) p += __shfl_xor(p, off, 64);
    if (lane == 0) sc[s] = p * 0.04419417382415922f;   // 1/sqrt(512)
  }
  __syncthreads();
  float val = (tid < NS) ? sc[tid] : -3.0e38f;
  float m = val;
  #pragma unroll
  for (int off = 32; off; off >>= 1) m = fmaxf(m, __shfl_xor(m, off, 64));
  if (lane == 0) red[wid] = m;
  __syncthreads();
  m = fmaxf(fmaxf(red[0], red[1]), fmaxf(red[2], red[3]));
  float e = (tid < NS) ? __expf(val - m) : 0.f;
  float sum = e;
  #pragma unroll
  for (int off = 32; off; off >>= 1) sum += __shfl_xor(sum, off, 64);
  if (lane == 0) red[4 + wid] = sum;
  __syncthreads();
  const float ssum = red[4] + red[5] + red[6] + red[7];
  wgt[tid] = e / ssum;
  __syncthreads();
  float a0 = 0.f, a1 = 0.f;
  const int h0 = tid * 2;
  for (int s = 0; s < NS; ++s) {
    const float w = wgt[s];
    u32 pr = *(const u32*)(base + (size_t)s * 512 + h0);
    a0 += w * b2f((u16)(pr & 0xFFFFu));
    a1 += w * b2f((u16)(pr >> 16));
  }
  ATTN[(size_t)b * 512 + h0] = a0;
  ATTN[(size_t)b * 512 + h0 + 1] = a1;
}

// 4 batch rows per WG: WT re-read traffic 256MB -> 64MB
__global__ void out_k(const float* __restrict__ ATTN, const float* __restrict__ Ain,
                      const float* __restrict__ WT, const float* __restrict__ bout,
                      float* __restrict__ OUT){
  const int g = blockIdx.x, tid = threadIdx.x;
  __shared__ float ah[4][520];
  for (int i = tid; i < 4 * 520; i += 256) {
    int bb = i / 520, k = i % 520;
    int b = g * 4 + bb;
    ah[bb][k] = (k < 512) ? ATTN[(size_t)b * 512 + k] : Ain[b * 8 + (k - 512)];
  }
  __syncthreads();
  #pragma unroll
  for (int part = 0; part < 2; ++part) {
    const int ho = part * 256 + tid;
    float a0 = bout[ho], a1 = a0, a2 = a0, a3 = a0;
    for (int k = 0; k < 520; ++k) {
      float w = WT[(size_t)k * 512 + ho];
      a0 += ah[0][k] * w; a1 += ah[1][k] * w; a2 += ah[2][k] * w; a3 += ah[3][k] * w;
    }
    OUT[(size_t)(g * 4 + 0) * 512 + ho] = a0;
    OUT[(size_t)(g * 4 + 1) * 512 + ho] = a1;
    OUT[(size_t)(g * 4 + 2) * 512 + ho] = a2;
    OUT[(size_t)(g * 4 + 3) * 512 + ho] = a3;
  }
}

// ---------------- host ----------------

extern "C" void kernel_launch(void* const* d_in, const int* in_sizes, int n_in,
                              void* d_out, int out_size, void* d_ws, size_t ws_size,
                              hipStream_t stream) {
  (void)in_sizes; (void)n_in; (void)out_size; (void)ws_size;
  const float* x    = (const float*)d_in[0];
  const float* a_in = (const float*)d_in[1];
  const float* tc   = (const float*)d_in[2];
  const float* mask = (const float*)d_in[3];
  const float* wdgx = (const float*)d_in[4];
  const float* bdgx = (const float*)d_in[5];
  const float* Wdgh = (const float*)d_in[6];
  const float* bdgh = (const float*)d_in[7];
  const float* Wm   = (const float*)d_in[8];
  const float* Um   = (const float*)d_in[9];
  const float* Vm   = (const float*)d_in[10];
  const float* bvv  = (const float*)d_in[11];
  const float* attv = (const float*)d_in[12];
  const float* Wout = (const float*)d_in[13];
  const float* bout = (const float*)d_in[14];

  char* ws = (char*)d_ws;
  size_t o = 0;
  auto al = [&](size_t sz) { size_t r = o; o += (sz + 255) & ~(size_t)255; return r; };
  u32*   flags = (u32*)  (ws + al(16 * 32 * 4));
  float* XMEAN = (float*)(ws + al(256));
  float* PX    = (float*)(ws + al((size_t)NS * 64 * 4));
  float* PM    = (float*)(ws + al((size_t)NS * 64 * 4));
  u16*   XHAT  = (u16*)  (ws + al((size_t)NS * NB * 64 * 2));
  u16*   MASKB = (u16*)  (ws + al((size_t)NS * NB * 64 * 2));
  u16*   DELTA = (u16*)  (ws + al((size_t)NS * NB * 64 * 2));
  u16*   UrP   = (u16*)  (ws + al((size_t)512 * 64 * 8 * 2));     // 512 KB
  u16*   HDEC2 = (u16*)  (ws + al((size_t)2 * NB * NH * 2));      // 512 KB
  u16*   XP    = (u16*)  (ws + al((size_t)NS * NB * 1536 * 2));   // 157 MB
  u16*   HALL  = (u16*)  (ws + al((size_t)NS * NB * NH * 2));     // 52 MB
  float* ATTN  = (float*)(ws + al((size_t)NB * NH * 4));
  float* WT    = (float*)(ws + al((size_t)520 * 512 * 4));

  hipMemsetAsync(flags, 0, 16 * 32 * 4, stream);

  transpose_k<<<(520 * 512 + 255) / 256, 256, 0, stream>>>(Wout, WT);
  wconv_k<<<(512 * 64 + 255) / 256, 256, 0, stream>>>(Um, UrP);
  mean1_k<<<NS, 256, 0, stream>>>(x, mask, PX, PM);
  mean2_k<<<1, 64, 0, stream>>>(PX, PM, XMEAN);
  prep_k<<<NB * ND / 256, 256, 0, stream>>>(x, mask, tc, wdgx, bdgx, XMEAN, XHAT, MASKB, DELTA);
  xpart_k<<<800, 256, 0, stream>>>(Wm, Vm, bvv, XHAT, MASKB, XP);
  grud_rnn<<<64, 256, 0, stream>>>(Um, UrP, Wdgh, bdgh, XP, DELTA, HDEC2, HALL, flags);
  attn_k<<<NB, 256, 0, stream>>>(HALL, attv, ATTN);
  out_k<<<64, 256, 0, stream>>>(ATTN, a_in, WT, bout, (float*)d_out);
}

// Round 16
// 1862.740 us; speedup vs baseline: 2.8398x; 2.8398x over previous
//
#include <hip/hip_runtime.h>
#include <hip/hip_bf16.h>
#include <stdint.h>

// GRU-D encoder, MI355X, round 16 = round 13 (session-best) restored.
// B=256, S=200, D=64, H=512, TD=8.
// XP[t,b,1536] precomputed -> recurrent GEMMs K=512; 16 rb x 4 gate WGs;
// resident weights (100 frags); cooperative LDS staging; store-flags with
// all-lane polls; 2 barriers + 2 polls + 2 publishes per step.
// The ~7.6us/step is cross-WG dependency latency (2 device-coherence-point
// round trips) -- measured floor of this dataflow on this chip.

typedef unsigned short u16;
typedef unsigned int   u32;
typedef unsigned long long u64;
typedef short bfrag  __attribute__((ext_vector_type(8)));
typedef u16   u16x8  __attribute__((ext_vector_type(8)));
typedef float f32x4  __attribute__((ext_vector_type(4)));

#define NB 256
#define NS 200
#define ND 64
#define NH 512

#define MFMA(a,b,c) __builtin_amdgcn_mfma_f32_16x16x32_bf16((a),(b),(c),0,0,0)

union UQ { u16x8 h; bfrag s; u64 u[2]; uint4 q; };

__device__ __forceinline__ float b2f(u16 v){ union { float f; u32 u; } c; c.u = ((u32)v) << 16; return c.f; }
__device__ __forceinline__ u16 f2b(float f){ union { float f; u32 u; } c; c.f = f; u32 r = c.u + 0x7FFFu + ((c.u >> 16) & 1u); return (u16)(r >> 16); }
__device__ __forceinline__ float sigm(float x){ return 1.f / (1.f + __expf(-x)); }
__device__ __forceinline__ float tanh_f(float x){ return 1.f - 2.f / (1.f + __expf(2.f * x)); }

// agent-scope (coherence-point) ops for intra-kernel cross-WG data
__device__ __forceinline__ u64 cload64(const void* p){
  return __hip_atomic_load((const u64*)p, __ATOMIC_RELAXED, __HIP_MEMORY_SCOPE_AGENT);
}
__device__ __forceinline__ void cstore64(void* p, u64 v){
  __hip_atomic_store((u64*)p, v, __ATOMIC_RELAXED, __HIP_MEMORY_SCOPE_AGENT);
}
__device__ __forceinline__ u32 cload32(const u32* p){
  return __hip_atomic_load(p, __ATOMIC_RELAXED, __HIP_MEMORY_SCOPE_AGENT);
}
__device__ __forceinline__ void cstore32(u32* p, u32 v){
  __hip_atomic_store(p, v, __ATOMIC_RELAXED, __HIP_MEMORY_SCOPE_AGENT);
}
// lane-parallel poll with backoff, fuel-bounded (fail fast, no GPU hang)
__device__ __forceinline__ bool poll_ge(const u32* wp, u32 tgt){
  int fuel = 1 << 19;
  while (true) {
    u32 v = cload32(wp);
    if (__all(v >= tgt)) return true;
    __builtin_amdgcn_s_sleep(1);
    if (--fuel == 0) return false;
  }
}
__device__ __forceinline__ bfrag ldfrag(const float* src){
  f32x4 lo = *(const f32x4*)src;
  f32x4 hi = *(const f32x4*)(src + 4);
  UQ z;
  z.h[0]=f2b(lo[0]); z.h[1]=f2b(lo[1]); z.h[2]=f2b(lo[2]); z.h[3]=f2b(lo[3]);
  z.h[4]=f2b(hi[0]); z.h[5]=f2b(hi[1]); z.h[6]=f2b(hi[2]); z.h[7]=f2b(hi[3]);
  return z.s;
}
// cooperative coalesced staging of a [16][512] bf16 block into an A-panel
__device__ __forceinline__ void stage_bf16(u16* dst, const u16* src, int tid, bool zero){
  const int row = tid >> 4, sc = (tid & 15) * 32;
  u16* dp = &dst[((sc >> 3) * 16 + row) * 8];
  if (!zero) {
    const u16* hs = src + (size_t)row * 512 + sc;
    u64 a0 = cload64(hs),      a1 = cload64(hs + 4),  a2 = cload64(hs + 8),  a3 = cload64(hs + 12);
    u64 a4 = cload64(hs + 16), a5 = cload64(hs + 20), a6 = cload64(hs + 24), a7 = cload64(hs + 28);
    *(u64*)(dp)       = a0; *(u64*)(dp + 4)   = a1;
    *(u64*)(dp + 128) = a2; *(u64*)(dp + 132) = a3;
    *(u64*)(dp + 256) = a4; *(u64*)(dp + 260) = a5;
    *(u64*)(dp + 384) = a6; *(u64*)(dp + 388) = a7;
  } else {
    *(u64*)(dp)       = 0; *(u64*)(dp + 4)   = 0;
    *(u64*)(dp + 128) = 0; *(u64*)(dp + 132) = 0;
    *(u64*)(dp + 256) = 0; *(u64*)(dp + 260) = 0;
    *(u64*)(dp + 384) = 0; *(u64*)(dp + 388) = 0;
  }
}

// ---------------- setup kernels ----------------

__global__ void transpose_k(const float* __restrict__ Wout, float* __restrict__ WT){
  int i = blockIdx.x * 256 + threadIdx.x;
  if (i < 520 * 512) { int k = i >> 9, ho = i & 511; WT[i] = Wout[ho * 520 + k]; }
}

__global__ void mean1_k(const float* __restrict__ x, const float* __restrict__ mask,
                        float* __restrict__ PX, float* __restrict__ PM){
  int s = blockIdx.x, tid = threadIdx.x;
  __shared__ float lx[256], lm[256];
  float xa = 0.f, ma = 0.f;
  for (int i = tid; i < NB * ND; i += 256) {
    int b = i >> 6, d = i & 63;
    size_t ix = ((size_t)b * NS + s) * 64 + d;
    float m = mask[ix];
    xa += m * x[ix]; ma += m;
  }
  lx[tid] = xa; lm[tid] = ma;
  __syncthreads();
  if (tid < 64) {
    PX[(size_t)s * 64 + tid] = lx[tid] + lx[tid + 64] + lx[tid + 128] + lx[tid + 192];
    PM[(size_t)s * 64 + tid] = lm[tid] + lm[tid + 64] + lm[tid + 128] + lm[tid + 192];
  }
}

__global__ void mean2_k(const float* __restrict__ PX, const float* __restrict__ PM,
                        float* __restrict__ XMEAN){
  int d = threadIdx.x;
  float sx = 0.f, sm = 0.f;
  for (int s = 0; s < NS; ++s){ sx += PX[s * 64 + d]; sm += PM[s * 64 + d]; }
  XMEAN[d] = sx / fmaxf(sm, 1.f);
}

__global__ void prep_k(const float* __restrict__ x, const float* __restrict__ mask,
                       const float* __restrict__ tc, const float* __restrict__ wdgx,
                       const float* __restrict__ bdgx, const float* __restrict__ XMEAN,
                       u16* __restrict__ XHAT, u16* __restrict__ MASKB, u16* __restrict__ DELTA){
  int g = blockIdx.x * 256 + threadIdx.x;
  int b = g >> 6, d = g & 63;
  float xmean = XMEAN[d], wx = wdgx[d], bx = bdgx[d];
  float xl = 0.f, del = 0.f, tprev = 0.f, mprev = 1.f;
  for (int s = 0; s < NS; ++s){
    float tv = tc[b * NS + s];
    float dtv = (s == 0) ? 0.f : (tv - tprev);
    tprev = tv;
    del = dtv + (1.f - mprev) * del;
    size_t ix = ((size_t)b * NS + s) * 64 + d;
    float m = mask[ix], xv = x[ix];
    float gx = __expf(-fmaxf(0.f, wx * del + bx));
    float xh = m * xv + (1.f - m) * (gx * xl + (1.f - gx) * xmean);
    size_t ox = ((size_t)s * NB + b) * 64 + d;
    XHAT[ox] = f2b(xh); MASKB[ox] = f2b(m); DELTA[ox] = f2b(del);
    xl = m * xv + (1.f - m) * xl;
    mprev = m;
  }
}

// ---------------- XP precompute ----------------
// XP[row][1536] = [x_hat|m](row) @ [W|V]^T + b for all 51200 rows.
__global__ __launch_bounds__(256, 1) void xpart_k(
    const float* __restrict__ Wm, const float* __restrict__ Vm,
    const float* __restrict__ bv, const u16* __restrict__ XHAT,
    const u16* __restrict__ MASKB, u16* __restrict__ XP){
  const int tid = threadIdx.x, lane = tid & 63, wid = tid >> 6;
  const int l16 = lane & 15, krow = lane >> 4, r4 = lane >> 2, cb = (lane & 3) * 8;
  const int chunk = blockIdx.x >> 1, p = blockIdx.x & 1;
  const int R0 = chunk * 128;
  const int wbasel = wid * 192;
  const int wbaseg = p * 768 + wbasel;
  __shared__ u16 panel[16 * 16 * 8];
  __shared__ u16 outs[16][768];
  __shared__ float xb[4][16 * 33];
  float* xw = xb[wid];
  const f32x4 Z4 = {0.f, 0.f, 0.f, 0.f};

  bfrag BW[12][2], BV2[12][2];
  #pragma unroll
  for (int ct = 0; ct < 12; ++ct)
    #pragma unroll
    for (int kx = 0; kx < 2; ++kx) {
      BW[ct][kx]  = ldfrag(Wm + (size_t)(wbaseg + ct * 16 + l16) * 64 + kx * 32 + krow * 8);
      BV2[ct][kx] = ldfrag(Vm + (size_t)(wbaseg + ct * 16 + l16) * 64 + kx * 32 + krow * 8);
    }
  float bias6[6][8];
  #pragma unroll
  for (int grp = 0; grp < 6; ++grp)
    #pragma unroll
    for (int q = 0; q < 8; ++q) bias6[grp][q] = bv[wbaseg + grp * 32 + cb + q];

  for (int it = 0; it < 8; ++it) {
    const int R = R0 + it * 16;
    { const int kb = tid >> 4, row = tid & 15;
      const u16* sp = (kb < 8 ? XHAT : MASKB) + (size_t)(R + row) * 64 + (kb & 7) * 8;
      *(uint4*)&panel[(kb * 16 + row) * 8] = *(const uint4*)sp; }
    __syncthreads();
    #pragma unroll
    for (int grp = 0; grp < 6; ++grp) {
      f32x4 ac0 = Z4, ac1 = Z4;
      #pragma unroll
      for (int kx = 0; kx < 2; ++kx) {
        bfrag ax = *(const bfrag*)&panel[((kx * 4 + krow) * 16 + l16) * 8];
        ac0 = MFMA(ax, BW[grp*2][kx], ac0); ac1 = MFMA(ax, BW[grp*2+1][kx], ac1);
        bfrag am = *(const bfrag*)&panel[((8 + kx * 4 + krow) * 16 + l16) * 8];
        ac0 = MFMA(am, BV2[grp*2][kx], ac0); ac1 = MFMA(am, BV2[grp*2+1][kx], ac1);
      }
      #pragma unroll
      for (int j = 0; j < 4; ++j) { xw[(krow*4+j)*33 + l16] = ac0[j]; xw[(krow*4+j)*33 + 16 + l16] = ac1[j]; }
      UQ ov;
      #pragma unroll
      for (int q = 0; q < 8; ++q) ov.h[q] = f2b(xw[r4 * 33 + cb + q] + bias6[grp][q]);
      *(u64*)&outs[r4][wbasel + grp * 32 + cb] = ov.u[0];
      *(u64*)&outs[r4][wbasel + grp * 32 + cb + 4] = ov.u[1];
    }
    __syncthreads();
    for (int c = tid; c < 16 * 96; c += 256) {
      const int row = c / 96, ch = c % 96;
      *(uint4*)(XP + (size_t)(R + row) * 1536 + p * 768 + ch * 8) =
          *(const uint4*)&outs[row][ch * 8];
    }
    __syncthreads();
  }
}

// ---------------- persistent recurrent kernel ----------------
// grid = 64 WGs (16 rb x 4 gate WGs), 256 threads (4 waves).
// XCD-colocating map: lid = (bid&7)*8 + (bid>>3); rb = lid>>2; g = lid&3.
// Flags per rb (stride 32 u32): FH[16]@0, FR[16]@16.
// 2 barriers/step; every wave polls the flag vector itself (all 64 lanes).
__global__ __launch_bounds__(256, 1) void grud_rnn(
    const float* __restrict__ Um, const float* __restrict__ Wdg, const float* __restrict__ bdg,
    const u16* __restrict__ XP, const u16* __restrict__ DELTA,
    u16* __restrict__ HDECB, u16* __restrict__ RHB, u16* __restrict__ HALL,
    u32* __restrict__ flags)
{
  const int tid = threadIdx.x, lane = tid & 63, wid = tid >> 6, bid = blockIdx.x;
  const int lid = (bid & 7) * 8 + (bid >> 3);
  const int rb = lid >> 2, g = lid & 3, m0 = rb * 16;
  const int l16 = lane & 15, krow = lane >> 4, r4 = lane >> 2, cb = (lane & 3) * 8;
  const int pw = g * 4 + wid;
  const int cw = g * 128 + wid * 32;
  u32* FB = flags + rb * 32;

  __shared__ u16 hpan[64 * 16 * 8];
  __shared__ u16 rpan[64 * 16 * 8];
  __shared__ u16 dpan[8 * 16 * 8];
  __shared__ float xb[4][16 * 33];
  __shared__ int s_ab;
  float* xw = xb[wid];
  const f32x4 Z4 = {0.f, 0.f, 0.f, 0.f};
  if (tid == 0) s_ab = 0;
  __syncthreads();

  bfrag BZ[16][2], BR[16][2], BH[16][2], BG[2][2];
  #pragma unroll
  for (int kk = 0; kk < 16; ++kk) {
    const size_t ko = (size_t)(kk * 32 + krow * 8);
    #pragma unroll
    for (int t2 = 0; t2 < 2; ++t2) {
      BZ[kk][t2] = ldfrag(Um + (size_t)(       cw + t2 * 16 + l16) * 512 + ko);
      BR[kk][t2] = ldfrag(Um + (size_t)(512  + cw + t2 * 16 + l16) * 512 + ko);
      BH[kk][t2] = ldfrag(Um + (size_t)(1024 + cw + t2 * 16 + l16) * 512 + ko);
    }
  }
  #pragma unroll
  for (int kk = 0; kk < 2; ++kk)
    #pragma unroll
    for (int t2 = 0; t2 < 2; ++t2)
      BG[kk][t2] = ldfrag(Wdg + (size_t)(cw + t2 * 16 + l16) * 64 + kk * 32 + krow * 8);
  float gb8[8];
  #pragma unroll
  for (int q = 0; q < 8; ++q) gb8[q] = bdg[cw + cb + q];

  const int slot = ((cw + cb) >> 3) * 16 + r4;

  for (int t = 0; t < NS; ++t) {
    const int tn = (t + 1 < NS) ? t + 1 : NS - 1;
    // static per-t loads before the poll (plain cached)
    const u16* xp = XP + ((size_t)t * NB + m0 + r4) * 1536 + cw + cb;
    u64 xz0 = *(const u64*)(xp),        xz1 = *(const u64*)(xp + 4);
    u64 xr0 = *(const u64*)(xp + 512),  xr1 = *(const u64*)(xp + 516);
    u64 xh0 = *(const u64*)(xp + 1024), xh1 = *(const u64*)(xp + 1028);
    // ---- hop 1: every wave polls FH itself, then stages immediately ----
    if (t > 0) { if (!poll_ge(FB + (lane & 15), (u32)t)) s_ab = 1; }
    stage_bf16(hpan, HDECB + (size_t)m0 * 512, tid, t == 0);
    if (tid < 128) {
      const int kb = tid >> 4, row = tid & 15;
      const u16* sp = DELTA + ((size_t)tn * NB + m0 + row) * 64 + kb * 8;
      *(uint4*)&dpan[(kb * 16 + row) * 8] = *(const uint4*)sp;
    }
    __syncthreads();                          // B1
    if (s_ab) break;
    // ---- r GEMM (K=512) ----
    f32x4 aR0 = Z4, aR1 = Z4;
    #pragma unroll
    for (int kk = 0; kk < 16; ++kk) {
      bfrag a = *(const bfrag*)&hpan[((kk * 4 + krow) * 16 + l16) * 8];
      aR0 = MFMA(a, BR[kk][0], aR0); aR1 = MFMA(a, BR[kk][1], aR1);
    }
    #pragma unroll
    for (int j = 0; j < 4; ++j) { xw[(krow*4+j)*33 + l16] = aR0[j]; xw[(krow*4+j)*33 + 16 + l16] = aR1[j]; }
    UQ hd_; hd_.h = *(const u16x8*)&hpan[slot * 8];
    UQ xr_; xr_.u[0] = xr0; xr_.u[1] = xr1;
    UQ rh_;
    #pragma unroll
    for (int q = 0; q < 8; ++q) {
      float rv = sigm(b2f(xr_.h[q]) + xw[r4 * 33 + cb + q]);
      rh_.h[q] = f2b(rv * b2f(hd_.h[q]));
    }
    u16* rdst = RHB + (size_t)(m0 + r4) * 512 + cw + cb;
    cstore64(rdst, rh_.u[0]); cstore64(rdst + 4, rh_.u[1]);
    asm volatile("s_waitcnt vmcnt(0)" ::: "memory");
    if (lane == 0) cstore32(FB + 16 + pw, (u32)(t + 1));
    // ---- z GEMM + gamma GEMM fill the rh round-trip window ----
    f32x4 aZ0 = Z4, aZ1 = Z4;
    #pragma unroll
    for (int kk = 0; kk < 16; ++kk) {
      bfrag a = *(const bfrag*)&hpan[((kk * 4 + krow) * 16 + l16) * 8];
      aZ0 = MFMA(a, BZ[kk][0], aZ0); aZ1 = MFMA(a, BZ[kk][1], aZ1);
    }
    #pragma unroll
    for (int j = 0; j < 4; ++j) { xw[(krow*4+j)*33 + l16] = aZ0[j]; xw[(krow*4+j)*33 + 16 + l16] = aZ1[j]; }
    UQ xz_; xz_.u[0] = xz0; xz_.u[1] = xz1;
    float zf[8];
    #pragma unroll
    for (int q = 0; q < 8; ++q) zf[q] = sigm(b2f(xz_.h[q]) + xw[r4 * 33 + cb + q]);
    f32x4 g0 = Z4, g1 = Z4;
    #pragma unroll
    for (int kk = 0; kk < 2; ++kk) {
      bfrag a = *(const bfrag*)&dpan[((kk * 4 + krow) * 16 + l16) * 8];
      g0 = MFMA(a, BG[kk][0], g0); g1 = MFMA(a, BG[kk][1], g1);
    }
    #pragma unroll
    for (int j = 0; j < 4; ++j) { xw[(krow*4+j)*33 + l16] = g0[j]; xw[(krow*4+j)*33 + 16 + l16] = g1[j]; }
    float gm8[8];
    #pragma unroll
    for (int q = 0; q < 8; ++q)
      gm8[q] = __expf(-fmaxf(0.f, xw[r4 * 33 + cb + q] + gb8[q]));
    // ---- hop 2: every wave polls FR itself, stages rpan ----
    if (!poll_ge(FB + 16 + (lane & 15), (u32)(t + 1))) s_ab = 1;
    stage_bf16(rpan, RHB + (size_t)m0 * 512, tid, false);
    __syncthreads();                          // B2
    if (s_ab) break;
    // ---- h-candidate GEMM (K=512) + blend + publish ----
    f32x4 aH0 = Z4, aH1 = Z4;
    #pragma unroll
    for (int kk = 0; kk < 16; ++kk) {
      bfrag a = *(const bfrag*)&rpan[((kk * 4 + krow) * 16 + l16) * 8];
      aH0 = MFMA(a, BH[kk][0], aH0); aH1 = MFMA(a, BH[kk][1], aH1);
    }
    #pragma unroll
    for (int j = 0; j < 4; ++j) { xw[(krow*4+j)*33 + l16] = aH0[j]; xw[(krow*4+j)*33 + 16 + l16] = aH1[j]; }
    UQ xh_; xh_.u[0] = xh0; xh_.u[1] = xh1;
    UQ hw_, hdn_;
    #pragma unroll
    for (int q = 0; q < 8; ++q) {
      float til = tanh_f(b2f(xh_.h[q]) + xw[r4 * 33 + cb + q]);
      float hn = (1.f - zf[q]) * b2f(hd_.h[q]) + zf[q] * til;
      hw_.h[q] = f2b(hn);
      hdn_.h[q] = f2b(gm8[q] * hn);
    }
    if (t + 1 < NS) {
      u16* hdst = HDECB + (size_t)(m0 + r4) * 512 + cw + cb;
      cstore64(hdst, hdn_.u[0]); cstore64(hdst + 4, hdn_.u[1]);
    }
    asm volatile("s_waitcnt vmcnt(0)" ::: "memory");
    if (lane == 0) cstore32(FB + 0 + pw, (u32)(t + 1));
    // HALL store off critical path; [b][s][h] layout for coalesced attn reads
    u16* hp = HALL + ((size_t)(m0 + r4) * NS + t) * 512 + cw + cb;
    *(u64*)hp = hw_.u[0]; *(u64*)(hp + 4) = hw_.u[1];
    // no end barrier: next-iter staging is ordered by the FH/FR polls
  }
}

// ---------------- post kernels ----------------

// HALL is [b][s][h]; all reads coalesced.
__global__ __launch_bounds__(256) void attn_k(const u16* __restrict__ HALL,
                                              const float* __restrict__ av,
                                              float* __restrict__ ATTN){
  const int b = blockIdx.x, tid = threadIdx.x, lane = tid & 63, wid = tid >> 6;
  __shared__ float avs[512], sc[256], wgt[256], red[8];
  for (int i = tid; i < 512; i += 256) avs[i] = av[i];
  __syncthreads();
  const u16* base = HALL + (size_t)b * NS * 512;
  for (int i = 0; i < 50; ++i) {
    const int s = wid * 50 + i;
    UQ w8; w8.q = *(const uint4*)(base + (size_t)s * 512 + lane * 8);
    float p = 0.f;
    #pragma unroll
    for (int j = 0; j < 8; ++j) p += b2f(w8.h[j]) * avs[lane * 8 + j];
    #pragma unroll
    for (int off = 32; off; off >>= 1) p += __shfl_xor(p, off, 64);
    if (lane == 0) sc[s] = p * 0.04419417382415922f;   // 1/sqrt(512)
  }
  __syncthreads();
  float val = (tid < NS) ? sc[tid] : -3.0e38f;
  float m = val;
  #pragma unroll
  for (int off = 32; off; off >>= 1) m = fmaxf(m, __shfl_xor(m, off, 64));
  if (lane == 0) red[wid] = m;
  __syncthreads();
  m = fmaxf(fmaxf(red[0], red[1]), fmaxf(red[2], red[3]));
  float e = (tid < NS) ? __expf(val - m) : 0.f;
  float sum = e;
  #pragma unroll
  for (int off = 32; off; off >>= 1) sum += __shfl_xor(sum, off, 64);
  if (lane == 0) red[4 + wid] = sum;
  __syncthreads();
  const float ssum = red[4] + red[5] + red[6] + red[7];
  wgt[tid] = e / ssum;
  __syncthreads();
  float a0 = 0.f, a1 = 0.f;
  const int h0 = tid * 2;
  for (int s = 0; s < NS; ++s) {
    const float w = wgt[s];
    u32 pr = *(const u32*)(base + (size_t)s * 512 + h0);
    a0 += w * b2f((u16)(pr & 0xFFFFu));
    a1 += w * b2f((u16)(pr >> 16));
  }
  ATTN[(size_t)b * 512 + h0] = a0;
  ATTN[(size_t)b * 512 + h0 + 1] = a1;
}

// 4 batch rows per WG: WT re-read traffic 256MB -> 64MB
__global__ void out_k(const float* __restrict__ ATTN, const float* __restrict__ Ain,
                      const float* __restrict__ WT, const float* __restrict__ bout,
                      float* __restrict__ OUT){
  const int g = blockIdx.x, tid = threadIdx.x;
  __shared__ float ah[4][520];
  for (int i = tid; i < 4 * 520; i += 256) {
    int bb = i / 520, k = i % 520;
    int b = g * 4 + bb;
    ah[bb][k] = (k < 512) ? ATTN[(size_t)b * 512 + k] : Ain[b * 8 + (k - 512)];
  }
  __syncthreads();
  #pragma unroll
  for (int part = 0; part < 2; ++part) {
    const int ho = part * 256 + tid;
    float a0 = bout[ho], a1 = a0, a2 = a0, a3 = a0;
    for (int k = 0; k < 520; ++k) {
      float w = WT[(size_t)k * 512 + ho];
      a0 += ah[0][k] * w; a1 += ah[1][k] * w; a2 += ah[2][k] * w; a3 += ah[3][k] * w;
    }
    OUT[(size_t)(g * 4 + 0) * 512 + ho] = a0;
    OUT[(size_t)(g * 4 + 1) * 512 + ho] = a1;
    OUT[(size_t)(g * 4 + 2) * 512 + ho] = a2;
    OUT[(size_t)(g * 4 + 3) * 512 + ho] = a3;
  }
}

// ---------------- host ----------------

extern "C" void kernel_launch(void* const* d_in, const int* in_sizes, int n_in,
                              void* d_out, int out_size, void* d_ws, size_t ws_size,
                              hipStream_t stream) {
  (void)in_sizes; (void)n_in; (void)out_size; (void)ws_size;
  const float* x    = (const float*)d_in[0];
  const float* a_in = (const float*)d_in[1];
  const float* tc   = (const float*)d_in[2];
  const float* mask = (const float*)d_in[3];
  const float* wdgx = (const float*)d_in[4];
  const float* bdgx = (const float*)d_in[5];
  const float* Wdgh = (const float*)d_in[6];
  const float* bdgh = (const float*)d_in[7];
  const float* Wm   = (const float*)d_in[8];
  const float* Um   = (const float*)d_in[9];
  const float* Vm   = (const float*)d_in[10];
  const float* bvv  = (const float*)d_in[11];
  const float* attv = (const float*)d_in[12];
  const float* Wout = (const float*)d_in[13];
  const float* bout = (const float*)d_in[14];

  char* ws = (char*)d_ws;
  size_t o = 0;
  auto al = [&](size_t sz) { size_t r = o; o += (sz + 255) & ~(size_t)255; return r; };
  u32*   flags = (u32*)  (ws + al(16 * 32 * 4));
  float* XMEAN = (float*)(ws + al(256));
  float* PX    = (float*)(ws + al((size_t)NS * 64 * 4));
  float* PM    = (float*)(ws + al((size_t)NS * 64 * 4));
  u16*   XHAT  = (u16*)  (ws + al((size_t)NS * NB * 64 * 2));
  u16*   MASKB = (u16*)  (ws + al((size_t)NS * NB * 64 * 2));
  u16*   DELTA = (u16*)  (ws + al((size_t)NS * NB * 64 * 2));
  u16*   HDECB = (u16*)  (ws + al((size_t)NB * NH * 2));
  u16*   RHB   = (u16*)  (ws + al((size_t)NB * NH * 2));
  u16*   XP    = (u16*)  (ws + al((size_t)NS * NB * 1536 * 2));   // 157 MB
  u16*   HALL  = (u16*)  (ws + al((size_t)NS * NB * NH * 2));     // 52 MB
  float* ATTN  = (float*)(ws + al((size_t)NB * NH * 4));
  float* WT    = (float*)(ws + al((size_t)520 * 512 * 4));

  hipMemsetAsync(flags, 0, 16 * 32 * 4, stream);

  transpose_k<<<(520 * 512 + 255) / 256, 256, 0, stream>>>(Wout, WT);
  mean1_k<<<NS, 256, 0, stream>>>(x, mask, PX, PM);
  mean2_k<<<1, 64, 0, stream>>>(PX, PM, XMEAN);
  prep_k<<<NB * ND / 256, 256, 0, stream>>>(x, mask, tc, wdgx, bdgx, XMEAN, XHAT, MASKB, DELTA);
  xpart_k<<<800, 256, 0, stream>>>(Wm, Vm, bvv, XHAT, MASKB, XP);
  grud_rnn<<<64, 256, 0, stream>>>(Um, Wdgh, bdgh, XP, DELTA, HDECB, RHB, HALL, flags);
  attn_k<<<NB, 256, 0, stream>>>(HALL, attv, ATTN);
  out_k<<<64, 256, 0, stream>>>(ATTN, a_in, WT, bout, (float*)d_out);
}